// Round 1
// baseline (358.234 us; speedup 1.0000x reference)
//
#include <hip/hip_runtime.h>
#include <hip/hip_bf16.h>
#include <math.h>

#define B_   2048
#define K_   256
#define AD_  512
#define IN_  768

// ---- f32 tiled GEMM config: C[m][n] = act(sum_k A[m][k]*W[n][k] + bias[n]) ----
#define BM 64
#define BN 64
#define BK 16

// GEMM1: A is the virtual concat [E|H|Q] (each [B,256] row-major), W1 [512,768], relu.
__global__ __launch_bounds__(256) void mlp1_kernel(
    const float* __restrict__ E, const float* __restrict__ H, const float* __restrict__ Q,
    const float* __restrict__ W1, const float* __restrict__ b1, float* __restrict__ H1)
{
    __shared__ float As[BM][BK + 1];
    __shared__ float Bs[BN][BK + 1];
    const int n0 = blockIdx.x * BN;
    const int m0 = blockIdx.y * BM;
    const int tid = threadIdx.x;
    const int tr = tid >> 4, tc = tid & 15;   // 16x16 thread grid, 4x4 micro-tile
    const int lrow = tid >> 2;                // 0..63
    const int lk   = (tid & 3) * 4;           // 0,4,8,12

    float acc[4][4] = {{0.f}};

    for (int k0 = 0; k0 < IN_; k0 += BK) {
        // BK=16 tile never straddles a 256 boundary -> pick source once per tile
        const float* src = (k0 < 256) ? E : (k0 < 512) ? H : Q;
        const int kb = k0 & 255;
        const float4 av = *(const float4*)&src[(size_t)(m0 + lrow) * 256 + kb + lk];
        As[lrow][lk + 0] = av.x; As[lrow][lk + 1] = av.y;
        As[lrow][lk + 2] = av.z; As[lrow][lk + 3] = av.w;
        const float4 bv = *(const float4*)&W1[(size_t)(n0 + lrow) * IN_ + k0 + lk];
        Bs[lrow][lk + 0] = bv.x; Bs[lrow][lk + 1] = bv.y;
        Bs[lrow][lk + 2] = bv.z; Bs[lrow][lk + 3] = bv.w;
        __syncthreads();
        #pragma unroll
        for (int kk = 0; kk < BK; ++kk) {
            float a[4], b[4];
            #pragma unroll
            for (int i = 0; i < 4; ++i) a[i] = As[tr * 4 + i][kk];
            #pragma unroll
            for (int j = 0; j < 4; ++j) b[j] = Bs[tc * 4 + j][kk];
            #pragma unroll
            for (int i = 0; i < 4; ++i)
                #pragma unroll
                for (int j = 0; j < 4; ++j)
                    acc[i][j] += a[i] * b[j];
        }
        __syncthreads();
    }
    #pragma unroll
    for (int i = 0; i < 4; ++i) {
        const int m = m0 + tr * 4 + i;
        #pragma unroll
        for (int j = 0; j < 4; ++j) {
            const int n = n0 + tc * 4 + j;
            float c = acc[i][j] + b1[n];
            c = fmaxf(c, 0.0f);   // relu
            H1[(size_t)m * AD_ + n] = c;
        }
    }
}

// GEMM2: X2 = H1 @ W2.T + b2 (no relu). A [2048,512], W2 [512,512].
__global__ __launch_bounds__(256) void mlp2_kernel(
    const float* __restrict__ A, const float* __restrict__ W2,
    const float* __restrict__ b2, float* __restrict__ X2)
{
    __shared__ float As[BM][BK + 1];
    __shared__ float Bs[BN][BK + 1];
    const int n0 = blockIdx.x * BN;
    const int m0 = blockIdx.y * BM;
    const int tid = threadIdx.x;
    const int tr = tid >> 4, tc = tid & 15;
    const int lrow = tid >> 2;
    const int lk   = (tid & 3) * 4;

    float acc[4][4] = {{0.f}};

    for (int k0 = 0; k0 < AD_; k0 += BK) {
        const float4 av = *(const float4*)&A[(size_t)(m0 + lrow) * AD_ + k0 + lk];
        As[lrow][lk + 0] = av.x; As[lrow][lk + 1] = av.y;
        As[lrow][lk + 2] = av.z; As[lrow][lk + 3] = av.w;
        const float4 bv = *(const float4*)&W2[(size_t)(n0 + lrow) * AD_ + k0 + lk];
        Bs[lrow][lk + 0] = bv.x; Bs[lrow][lk + 1] = bv.y;
        Bs[lrow][lk + 2] = bv.z; Bs[lrow][lk + 3] = bv.w;
        __syncthreads();
        #pragma unroll
        for (int kk = 0; kk < BK; ++kk) {
            float a[4], b[4];
            #pragma unroll
            for (int i = 0; i < 4; ++i) a[i] = As[tr * 4 + i][kk];
            #pragma unroll
            for (int j = 0; j < 4; ++j) b[j] = Bs[tc * 4 + j][kk];
            #pragma unroll
            for (int i = 0; i < 4; ++i)
                #pragma unroll
                for (int j = 0; j < 4; ++j)
                    acc[i][j] += a[i] * b[j];
        }
        __syncthreads();
    }
    #pragma unroll
    for (int i = 0; i < 4; ++i) {
        const int m = m0 + tr * 4 + i;
        #pragma unroll
        for (int j = 0; j < 4; ++j) {
            const int n = n0 + tc * 4 + j;
            X2[(size_t)m * AD_ + n] = acc[i][j] + b2[n];
        }
    }
}

// scores + masked softmax + entropy. One block per batch row, 4 waves.
// Wave handles one k at a time: 64 lanes x float4 = 256 floats per emb row.
__global__ __launch_bounds__(256) void scores_kernel(
    const float* __restrict__ X2, const float* __restrict__ emb_r,
    const float* __restrict__ emb_e, const float* __restrict__ mask,
    const int* __restrict__ r_space, const int* __restrict__ e_space,
    float* __restrict__ dist, float* __restrict__ entropy)
{
    const int b = blockIdx.x;
    const int tid = threadIdx.x;
    const int lane = tid & 63, wid = tid >> 6;

    __shared__ float s_sc[K_];
    __shared__ float s_red[8];

    // per-lane slice of X2[b]: first 256 (for emb_r), last 256 (for emb_e)
    const float4 xr = *(const float4*)&X2[(size_t)b * AD_ + lane * 4];
    const float4 xe = *(const float4*)&X2[(size_t)b * AD_ + 256 + lane * 4];

    for (int k = wid; k < K_; k += 4) {
        const int r = r_space[b * K_ + k];
        const int e = e_space[b * K_ + k];
        const float4 ar = *(const float4*)&emb_r[(size_t)r * 256 + lane * 4];
        const float4 ae = *(const float4*)&emb_e[(size_t)e * 256 + lane * 4];
        float p = ar.x * xr.x + ar.y * xr.y + ar.z * xr.z + ar.w * xr.w
                + ae.x * xe.x + ae.y * xe.y + ae.z * xe.z + ae.w * xe.w;
        #pragma unroll
        for (int off = 32; off >= 1; off >>= 1) p += __shfl_down(p, off);
        if (lane == 0) {
            const float mk = mask[b * K_ + k];
            s_sc[k] = p - (1.0f - mk) * 1e31f;
        }
    }
    __syncthreads();

    // --- block max ---
    const float v = s_sc[tid];
    float m = v;
    #pragma unroll
    for (int off = 32; off >= 1; off >>= 1) m = fmaxf(m, __shfl_down(m, off));
    if (lane == 0) s_red[wid] = m;
    __syncthreads();
    if (tid == 0)
        s_red[4] = fmaxf(fmaxf(s_red[0], s_red[1]), fmaxf(s_red[2], s_red[3]));
    __syncthreads();
    const float bmax = s_red[4];

    // --- block sum of exp ---
    const float ev = expf(v - bmax);   // masked entries: exp(-1e31 - max) == 0
    float s = ev;
    #pragma unroll
    for (int off = 32; off >= 1; off >>= 1) s += __shfl_down(s, off);
    __syncthreads();
    if (lane == 0) s_red[wid] = s;
    __syncthreads();
    if (tid == 0)
        s_red[5] = s_red[0] + s_red[1] + s_red[2] + s_red[3];
    __syncthreads();
    const float ssum = s_red[5];

    const float p = ev / ssum;
    dist[(size_t)b * K_ + tid] = p;

    // --- entropy: -sum p*log(p+1e-20) ---
    float t = p * logf(p + 1e-20f);
    #pragma unroll
    for (int off = 32; off >= 1; off >>= 1) t += __shfl_down(t, off);
    __syncthreads();
    if (lane == 0) s_red[wid] = t;
    __syncthreads();
    if (tid == 0)
        entropy[b] = -(s_red[0] + s_red[1] + s_red[2] + s_red[3]);
}

extern "C" void kernel_launch(void* const* d_in, const int* in_sizes, int n_in,
                              void* d_out, int out_size, void* d_ws, size_t ws_size,
                              hipStream_t stream) {
    const float* E     = (const float*)d_in[0];
    const float* H     = (const float*)d_in[1];
    const float* Q     = (const float*)d_in[2];
    const float* W1    = (const float*)d_in[3];
    const float* b1    = (const float*)d_in[4];
    const float* W2    = (const float*)d_in[5];
    const float* b2    = (const float*)d_in[6];
    const float* emb_r = (const float*)d_in[7];
    const float* emb_e = (const float*)d_in[8];
    const float* mask  = (const float*)d_in[9];
    const int* r_space = (const int*)d_in[10];
    const int* e_space = (const int*)d_in[11];

    float* out_dist = (float*)d_out;                      // [B,K]
    float* out_ent  = out_dist + (size_t)B_ * K_;         // [B]

    float* H1 = (float*)d_ws;                             // [B, AD] 4 MB
    float* X2 = H1 + (size_t)B_ * AD_;                    // [B, AD] 4 MB

    dim3 g(AD_ / BN, B_ / BM);   // (8, 32)
    mlp1_kernel<<<g, 256, 0, stream>>>(E, H, Q, W1, b1, H1);
    mlp2_kernel<<<g, 256, 0, stream>>>(H1, W2, b2, X2);
    scores_kernel<<<B_, 256, 0, stream>>>(X2, emb_r, emb_e, mask,
                                          r_space, e_space, out_dist, out_ent);
}

// Round 2
// 288.139 us; speedup vs baseline: 1.2433x; 1.2433x over previous
//
#include <hip/hip_runtime.h>
#include <hip/hip_bf16.h>
#include <math.h>

#define B_   2048
#define K_   256
#define AD_  512
#define IN_  768

typedef __attribute__((ext_vector_type(8))) short short8;
typedef __attribute__((ext_vector_type(4))) float float4v;

__device__ __forceinline__ unsigned short f2bf(float f) {
    unsigned int u = __float_as_uint(f);
    unsigned int r = u + 0x7FFF + ((u >> 16) & 1);   // round-to-nearest-even
    return (unsigned short)(r >> 16);
}

// cast concat [E|H|Q] f32 -> X bf16 [2048][768]; 4 elems/thread
__global__ __launch_bounds__(256) void cast_concat_kernel(
    const float* __restrict__ E, const float* __restrict__ H,
    const float* __restrict__ Q, ushort* __restrict__ X)
{
    const int t = blockIdx.x * 256 + threadIdx.x;     // 393216 threads
    const int base = t * 4;
    const int row = base / IN_, col = base % IN_;
    const float* src = (col < 256) ? &E[row * 256 + col]
                     : (col < 512) ? &H[row * 256 + col - 256]
                                   : &Q[row * 256 + col - 512];
    const float4 v = *(const float4*)src;
    ushort4 o;
    o.x = f2bf(v.x); o.y = f2bf(v.y); o.z = f2bf(v.z); o.w = f2bf(v.w);
    *(ushort4*)&X[base] = o;
}

__global__ __launch_bounds__(256) void cast_kernel(
    const float* __restrict__ in, ushort* __restrict__ out, int n4)
{
    const int t = blockIdx.x * 256 + threadIdx.x;
    if (t >= n4) return;
    const float4 v = *(const float4*)&in[t * 4];
    ushort4 o;
    o.x = f2bf(v.x); o.y = f2bf(v.y); o.z = f2bf(v.z); o.w = f2bf(v.w);
    *(ushort4*)&out[t * 4] = o;
}

// bf16 MFMA GEMM: C[m][n] = act(sum_k A[m][k]*Bw[n][k] + bias[n])
// A [M][K] bf16 row-major, Bw [N][K] bf16 row-major (i.e. B^T). Tile 64x64, 4 waves.
// Wave w: rows [16w,16w+16), 4 n-subtiles of 16. N fixed = 512 for output stride.
template<int K, bool RELU, bool OUT_BF16>
__global__ __launch_bounds__(256) void gemm_bf16_kernel(
    const ushort* __restrict__ A, const ushort* __restrict__ Bw,
    const float* __restrict__ bias, ushort* __restrict__ outb,
    float* __restrict__ outf)
{
    constexpr int PITCH = 40;                     // 32 + 8 pad (ushort units)
    __shared__ ushort Asl[64 * PITCH];
    __shared__ ushort Bsl[64 * PITCH];
    const int tid = threadIdx.x;
    const int lane = tid & 63, w = tid >> 6;
    const int n0 = blockIdx.x * 64, m0 = blockIdx.y * 64;
    const int lrow = tid >> 2, lcg = (tid & 3) * 8; // staging: 4 loaders/row

    const int q = lane >> 4, l16 = lane & 15;

    float4v acc[4] = {};
    for (int k0 = 0; k0 < K; k0 += 32) {
        *(short8*)&Asl[lrow * PITCH + lcg] =
            *(const short8*)&A[(size_t)(m0 + lrow) * K + k0 + lcg];
        *(short8*)&Bsl[lrow * PITCH + lcg] =
            *(const short8*)&Bw[(size_t)(n0 + lrow) * K + k0 + lcg];
        __syncthreads();
        // a_frag: A[m = l16][k = q*8 + j]
        const short8 af = *(const short8*)&Asl[(w * 16 + l16) * PITCH + q * 8];
        #pragma unroll
        for (int jn = 0; jn < 4; ++jn) {
            const short8 bf = *(const short8*)&Bsl[(jn * 16 + l16) * PITCH + q * 8];
            acc[jn] = __builtin_amdgcn_mfma_f32_16x16x32_bf16(af, bf, acc[jn], 0, 0, 0);
        }
        __syncthreads();
    }
    // C/D: row = q*4 + r, col = l16 within each 16x16 tile
    #pragma unroll
    for (int jn = 0; jn < 4; ++jn) {
        const int n = n0 + jn * 16 + l16;
        const float bn = bias[n];
        #pragma unroll
        for (int r = 0; r < 4; ++r) {
            const int m = m0 + w * 16 + q * 4 + r;
            float c = acc[jn][r] + bn;
            if (RELU) c = fmaxf(c, 0.0f);
            if (OUT_BF16) outb[(size_t)m * AD_ + n] = f2bf(c);
            else          outf[(size_t)m * AD_ + n] = c;
        }
    }
}

// scores + masked softmax + entropy. One block per batch row, 4 waves.
__global__ __launch_bounds__(256) void scores_kernel(
    const float* __restrict__ X2, const float* __restrict__ emb_r,
    const float* __restrict__ emb_e, const float* __restrict__ mask,
    const int* __restrict__ r_space, const int* __restrict__ e_space,
    float* __restrict__ dist, float* __restrict__ entropy)
{
    const int b = blockIdx.x;
    const int tid = threadIdx.x;
    const int lane = tid & 63, wid = tid >> 6;

    __shared__ float s_sc[K_];
    __shared__ float s_red[8];

    const float4 xr = *(const float4*)&X2[(size_t)b * AD_ + lane * 4];
    const float4 xe = *(const float4*)&X2[(size_t)b * AD_ + 256 + lane * 4];

    for (int k = wid; k < K_; k += 4) {
        const int r = r_space[b * K_ + k];
        const int e = e_space[b * K_ + k];
        const float4 ar = *(const float4*)&emb_r[(size_t)r * 256 + lane * 4];
        const float4 ae = *(const float4*)&emb_e[(size_t)e * 256 + lane * 4];
        float p = ar.x * xr.x + ar.y * xr.y + ar.z * xr.z + ar.w * xr.w
                + ae.x * xe.x + ae.y * xe.y + ae.z * xe.z + ae.w * xe.w;
        #pragma unroll
        for (int off = 32; off >= 1; off >>= 1) p += __shfl_down(p, off);
        if (lane == 0) {
            const float mk = mask[b * K_ + k];
            s_sc[k] = p - (1.0f - mk) * 1e31f;
        }
    }
    __syncthreads();

    const float v = s_sc[tid];
    float m = v;
    #pragma unroll
    for (int off = 32; off >= 1; off >>= 1) m = fmaxf(m, __shfl_down(m, off));
    if (lane == 0) s_red[wid] = m;
    __syncthreads();
    if (tid == 0)
        s_red[4] = fmaxf(fmaxf(s_red[0], s_red[1]), fmaxf(s_red[2], s_red[3]));
    __syncthreads();
    const float bmax = s_red[4];

    const float ev = expf(v - bmax);
    float s = ev;
    #pragma unroll
    for (int off = 32; off >= 1; off >>= 1) s += __shfl_down(s, off);
    __syncthreads();
    if (lane == 0) s_red[wid] = s;
    __syncthreads();
    if (tid == 0)
        s_red[5] = s_red[0] + s_red[1] + s_red[2] + s_red[3];
    __syncthreads();
    const float ssum = s_red[5];

    const float p = ev / ssum;
    dist[(size_t)b * K_ + tid] = p;

    float t = p * logf(p + 1e-20f);
    #pragma unroll
    for (int off = 32; off >= 1; off >>= 1) t += __shfl_down(t, off);
    __syncthreads();
    if (lane == 0) s_red[wid] = t;
    __syncthreads();
    if (tid == 0)
        entropy[b] = -(s_red[0] + s_red[1] + s_red[2] + s_red[3]);
}

extern "C" void kernel_launch(void* const* d_in, const int* in_sizes, int n_in,
                              void* d_out, int out_size, void* d_ws, size_t ws_size,
                              hipStream_t stream) {
    const float* E     = (const float*)d_in[0];
    const float* H     = (const float*)d_in[1];
    const float* Q     = (const float*)d_in[2];
    const float* W1    = (const float*)d_in[3];
    const float* b1    = (const float*)d_in[4];
    const float* W2    = (const float*)d_in[5];
    const float* b2    = (const float*)d_in[6];
    const float* emb_r = (const float*)d_in[7];
    const float* emb_e = (const float*)d_in[8];
    const float* mask  = (const float*)d_in[9];
    const int* r_space = (const int*)d_in[10];
    const int* e_space = (const int*)d_in[11];

    float* out_dist = (float*)d_out;
    float* out_ent  = out_dist + (size_t)B_ * K_;

    // workspace layout (bytes, 256-aligned)
    char* ws = (char*)d_ws;
    ushort* Xb   = (ushort*)ws;                        ws += (size_t)B_ * IN_ * 2;   // 3.0 MB
    ushort* W1b  = (ushort*)ws;                        ws += (size_t)AD_ * IN_ * 2;  // 0.75 MB
    ushort* W2b  = (ushort*)ws;                        ws += (size_t)AD_ * AD_ * 2;  // 0.5 MB
    ushort* H1b  = (ushort*)ws;                        ws += (size_t)B_ * AD_ * 2;   // 2.0 MB
    float*  X2   = (float*)ws;                         ws += (size_t)B_ * AD_ * 4;   // 4.0 MB

    cast_concat_kernel<<<(B_ * IN_ / 4) / 256, 256, 0, stream>>>(E, H, Q, Xb);
    cast_kernel<<<(AD_ * IN_ / 4 + 255) / 256, 256, 0, stream>>>(W1, W1b, AD_ * IN_ / 4);
    cast_kernel<<<(AD_ * AD_ / 4 + 255) / 256, 256, 0, stream>>>(W2, W2b, AD_ * AD_ / 4);

    dim3 g(AD_ / 64, B_ / 64);   // (8, 32) = 256 blocks
    gemm_bf16_kernel<IN_, true,  true ><<<g, 256, 0, stream>>>(Xb,  W1b, b1, H1b, nullptr);
    gemm_bf16_kernel<AD_, false, false><<<g, 256, 0, stream>>>(H1b, W2b, b2, nullptr, X2);

    scores_kernel<<<B_, 256, 0, stream>>>(X2, emb_r, emb_e, mask,
                                          r_space, e_space, out_dist, out_ent);
}